// Round 9
// baseline (48.155 us; speedup 1.0000x reference)
//
#include <hip/hip_runtime.h>

#define N_ROWS 262144
#define DIM    64
#define KCB    512

#define ABLOCKS  1024
#define ATHREADS 512         // 8 waves; each wave 32 rows = 2 chunks x 16
#define BTHREADS 256
#define BBLOCKS  ((N_ROWS * 16) / BTHREADS)   // 16 lanes per row

typedef float f32x4 __attribute__((ext_vector_type(4)));

__device__ inline float dot4(float4 a) {
    return a.x * a.x + a.y * a.y + a.z * a.z + a.w * a.w;
}
__device__ inline unsigned umin2(unsigned a, unsigned b) { return a < b ? a : b; }

// pack 8 f32 (scaled) into 8 fp8-e4m3 bytes via HW cvt_pk (4 instr)
__device__ inline long pk8(float4 f0, float4 f1, float s) {
    int lo = 0, hi = 0;
    lo = __builtin_amdgcn_cvt_pk_fp8_f32(f0.x * s, f0.y * s, lo, false);
    lo = __builtin_amdgcn_cvt_pk_fp8_f32(f0.z * s, f0.w * s, lo, true);
    hi = __builtin_amdgcn_cvt_pk_fp8_f32(f1.x * s, f1.y * s, hi, false);
    hi = __builtin_amdgcn_cvt_pk_fp8_f32(f1.z * s, f1.w * s, hi, true);
    return (long)(((unsigned long)(unsigned)hi << 32) | (unsigned)lo);
}

// ---- kernel A: stage fp8 codebook + wn, pipelined argmin, idx + loss -------
__global__ __launch_bounds__(ATHREADS, 2) void vq_score(
    const float* __restrict__ x, const float* __restrict__ cb,
    unsigned short* __restrict__ idx, float* __restrict__ partials)
{
    // A = -256*w, fp8 e4m3, 8B granules, row-pair interleaved + XOR swizzle
    // (R8-proven: 0 bank conflicts). wn = 256*(1+0.5||w||^2).
    __shared__ long   cb8_sh[KCB * 8];     // 32 KiB
    __shared__ f32x4  wn_sh4[KCB / 4];     // 2 KiB
    __shared__ float  red_sh[8];

    const int tid    = threadIdx.x;
    const int lane   = tid & 63;
    const int wave   = tid >> 6;           // 0..7
    const int lane15 = lane & 15;
    const int half   = lane >> 4;          // 0..3

    const int wrow = blockIdx.x * 256 + wave * 32;
    const float* xc = x + (size_t)(wrow + lane15) * DIM + half * 8;

    // ---- issue chunk0 (rows wrow..+16) loads: in flight during staging -----
    float4 p00 = *(const float4*)xc,        p01 = *(const float4*)(xc + 4);
    float4 p02 = *(const float4*)(xc + 32), p03 = *(const float4*)(xc + 36);

    // ---- stage codebook f32 -> fp8(-256w) into LDS; fold in wn -------------
    #pragma unroll
    for (int it = 0; it < (KCB * 8) / ATHREADS; ++it) {
        const int fg = tid + it * ATHREADS;
        const int row = fg >> 3, g = fg & 7;
        const float* src = cb + row * DIM + g * 8;
        float4 f0 = *(const float4*)src;
        float4 f1 = *(const float4*)(src + 4);
        float sq = dot4(f0) + dot4(f1);
        sq += __shfl_xor(sq, 1);
        sq += __shfl_xor(sq, 2);
        sq += __shfl_xor(sq, 4);
        const int slot = ((row >> 1) << 4) + ((row & 1) << 3)
                       + (g ^ ((row >> 1) & 7));
        cb8_sh[slot] = pk8(f0, f1, -256.0f);
        if (g == 0) ((float*)wn_sh4)[row] = 256.0f + 128.0f * sq;
    }

    // ---- convert chunk0 while the barrier drains ---------------------------
    float xn0 = dot4(p00) + dot4(p01) + dot4(p02) + dot4(p03);
    long b0lo = pk8(p00, p01, 1.0f), b0hi = pk8(p02, p03, 1.0f);
    __syncthreads();

    // ---- issue chunk1 (rows wrow+16..+32) loads: in flight during score0 ---
    float4 q00 = *(const float4*)(xc + 1024), q01 = *(const float4*)(xc + 1028);
    float4 q02 = *(const float4*)(xc + 1056), q03 = *(const float4*)(xc + 1060);

    // per-lane read slots (R8-proven conflict-free)
    const int key  = (lane15 >> 1) & 7;
    const int base = (lane15 >> 1) * 16 + (lane15 & 1) * 8;
    const int slo  = base + (half ^ key);          // dims [8*half, +8)
    const int shi  = slo ^ 4;                      // dims [32+8*half, +8)
    const unsigned hb   = (unsigned)(half * 4);
    const unsigned mask = 0xFFFFFE00u;

    float lossAcc = 0.f;
    long blo = b0lo, bhi = b0hi;
    float xn = xn0;

    #pragma unroll
    for (int ch = 0; ch < 2; ++ch) {
        if (ch == 1) {     // convert prefetched chunk1 (loads complete by now)
            xn  = dot4(q00) + dot4(q01) + dot4(q02) + dot4(q03);
            blo = pk8(q00, q01, 1.0f);
            bhi = pk8(q02, q03, 1.0f);
        }
        unsigned u0 = 0xFFFFFFFFu;

        #pragma unroll 8
        for (int t = 0; t < 32; ++t) {
            long  alo = cb8_sh[t * 128 + slo];
            long  ahi = cb8_sh[t * 128 + shi];
            f32x4 wnv = wn_sh4[t * 4 + half];
            const unsigned kb = (unsigned)(t * 16) | hb;

            f32x4 acc = wnv;   // acc = 256*(1+0.5||w||^2 - x.w) = 256*score > 0
            acc = __builtin_amdgcn_mfma_f32_16x16x32_fp8_fp8(alo, blo, acc, 0, 0, 0);
            acc = __builtin_amdgcn_mfma_f32_16x16x32_fp8_fp8(ahi, bhi, acc, 0, 0, 0);
            unsigned p0 = (__float_as_uint(acc[0]) & mask) | kb;
            unsigned p1 = (__float_as_uint(acc[1]) & mask) | (kb | 1u);
            unsigned p2 = (__float_as_uint(acc[2]) & mask) | (kb | 2u);
            unsigned p3 = (__float_as_uint(acc[3]) & mask) | (kb | 3u);
            u0 = umin2(u0, umin2(umin2(p0, p1), umin2(p2, p3)));
        }

        // ---- reduce across 4 halves (same lane15 = same x-row) -------------
        unsigned f0 = u0;
        f0 = umin2(f0, (unsigned)__shfl_xor((int)f0, 16));
        f0 = umin2(f0, (unsigned)__shfl_xor((int)f0, 32));
        float xs = xn;
        xs += __shfl_xor(xs, 16); xs += __shfl_xor(xs, 32);

        // packed score = 256*(1+0.5||q||^2-x.q); ||x-q||^2 = xs + pf/128 - 2
        // per lane 0.25*row-loss, 4 dup lanes -> wave sum = sum_rows (proven)
        float pf = __uint_as_float(f0 & mask);
        lossAcc += 0.25f * (xs + pf * (1.0f / 128.0f) - 2.0f);

        if (lane < 16) idx[wrow + ch * 16 + lane] = (unsigned short)(f0 & 511u);
    }

    // ---- loss partial ------------------------------------------------------
    #pragma unroll
    for (int off = 1; off < 64; off <<= 1) lossAcc += __shfl_xor(lossAcc, off);
    if (lane == 0) red_sh[wave] = lossAcc;
    __syncthreads();
    if (tid == 0) {
        float s = 0.f;
        #pragma unroll
        for (int w = 0; w < 8; ++w) s += red_sh[w];
        partials[blockIdx.x] = s;
    }
}

// ---- kernel B: pure coalesced gather-store ---------------------------------
__global__ __launch_bounds__(BTHREADS, 8) void vq_gather(
    const unsigned short* __restrict__ idx, const float* __restrict__ cb,
    float* __restrict__ out)
{
    const int g   = blockIdx.x * BTHREADS + threadIdx.x;  // 0 .. N*16-1
    const int row = g >> 4;
    const int dq  = g & 15;
    const int k   = (int)idx[row];
    const f32x4* cb4 = (const f32x4*)cb;
    ((f32x4*)out)[g] = cb4[k * 16 + dq];
}

// ---- kernel C: final loss reduction (1024 partials) ------------------------
__global__ void vq_finalize(const float* __restrict__ partials,
                            float* __restrict__ out_loss) {
    __shared__ float sh[256];
    int t = threadIdx.x;
    sh[t] = partials[t] + partials[t + 256] + partials[t + 512] + partials[t + 768];
    __syncthreads();
    #pragma unroll
    for (int s = 128; s > 0; s >>= 1) {
        if (t < s) sh[t] += sh[t + s];
        __syncthreads();
    }
    // partials = sum_rows ||x-q||^2 ; vq_loss = 1.25 * sum / (N*D)
    if (t == 0) out_loss[0] = sh[0] * (1.25f / (float)(N_ROWS * DIM));
}

extern "C" void kernel_launch(void* const* d_in, const int* in_sizes, int n_in,
                              void* d_out, int out_size, void* d_ws, size_t ws_size,
                              hipStream_t stream) {
    const float* x  = (const float*)d_in[0];
    const float* cb = (const float*)d_in[1];
    float* out      = (float*)d_out;
    float* partials = (float*)d_ws;                        // 1024 floats
    unsigned short* idx = (unsigned short*)((char*)d_ws + 4096);  // N u16

    hipLaunchKernelGGL(vq_score, dim3(ABLOCKS), dim3(ATHREADS), 0, stream,
                       x, cb, idx, partials);
    hipLaunchKernelGGL(vq_gather, dim3(BBLOCKS), dim3(BTHREADS), 0, stream,
                       idx, cb, out);
    hipLaunchKernelGGL(vq_finalize, dim3(1), dim3(256), 0, stream,
                       partials, out + (size_t)N_ROWS * DIM);
}

// Round 10
// 40.327 us; speedup vs baseline: 1.1941x; 1.1941x over previous
//
#include <hip/hip_runtime.h>

#define N_ROWS 262144
#define DIM    64
#define KCB    512

#define MBLOCKS  1024
#define MTHREADS 256         // 4 waves; each wave 64 rows = 4 chunks x 16

typedef float f32x4 __attribute__((ext_vector_type(4)));

__device__ inline float dot4(float4 a) {
    return a.x * a.x + a.y * a.y + a.z * a.z + a.w * a.w;
}
__device__ inline unsigned umin2(unsigned a, unsigned b) { return a < b ? a : b; }

// pack 8 f32 (scaled) into 8 fp8-e4m3 bytes via HW cvt_pk
__device__ inline long pk8(float4 f0, float4 f1, float s) {
    int lo = 0, hi = 0;
    lo = __builtin_amdgcn_cvt_pk_fp8_f32(f0.x * s, f0.y * s, lo, false);
    lo = __builtin_amdgcn_cvt_pk_fp8_f32(f0.z * s, f0.w * s, lo, true);
    hi = __builtin_amdgcn_cvt_pk_fp8_f32(f1.x * s, f1.y * s, hi, false);
    hi = __builtin_amdgcn_cvt_pk_fp8_f32(f1.z * s, f1.w * s, hi, true);
    return (long)(((unsigned long)(unsigned)hi << 32) | (unsigned)lo);
}

// ---- kernel 0: one-time codebook pre-pack into the exact LDS image ---------
// image: longs[0..4096) = fp8(-256*w) in interleaved+swizzled slots (32 KiB),
//        floats[8192..8704) = wn[k] = 256*(1+0.5||w||^2) (2 KiB)
__global__ void vq_prep(const float* __restrict__ cb, long* __restrict__ cb8,
                        float* __restrict__ wn) {
    const int fg  = blockIdx.x * 512 + threadIdx.x;   // 0..4095
    const int row = fg >> 3, g = fg & 7;
    const float* src = cb + row * DIM + g * 8;
    float4 f0 = *(const float4*)src;
    float4 f1 = *(const float4*)(src + 4);
    float sq = dot4(f0) + dot4(f1);
    sq += __shfl_xor(sq, 1);
    sq += __shfl_xor(sq, 2);
    sq += __shfl_xor(sq, 4);
    const int slot = ((row >> 1) << 4) + ((row & 1) << 3)
                   + (g ^ ((row >> 1) & 7));
    cb8[slot] = pk8(f0, f1, -256.0f);
    if (g == 0) wn[row] = 256.0f + 128.0f * sq;
}

// ---- kernel 1: fused, 4-chunk pipelined: load(i+1) | score(i) | store(i) ---
__global__ __launch_bounds__(MTHREADS, 4) void vq_main(
    const float* __restrict__ x, const float* __restrict__ cb,
    const f32x4* __restrict__ img_g, float* __restrict__ out,
    float* __restrict__ partials)
{
    __shared__ f32x4 img[2176];            // 34 KiB: cb8[2048] + wn[128]
    __shared__ float red_sh[4];

    const int tid    = threadIdx.x;
    const int lane   = tid & 63;
    const int wave   = tid >> 6;           // 0..3
    const int lane15 = lane & 15;
    const int half   = lane >> 4;          // 0..3

    const int wrow = blockIdx.x * 256 + wave * 64;
    const float* xc = x + (size_t)(wrow + lane15) * DIM + half * 8;

    // ---- issue chunk0 x loads (in flight during staging) -------------------
    float4 a0 = *(const float4*)xc,        a1 = *(const float4*)(xc + 4);
    float4 a2 = *(const float4*)(xc + 32), a3 = *(const float4*)(xc + 36);

    // ---- stage pre-packed image: pure linear 34 KiB copy, zero convert -----
    #pragma unroll
    for (int it = 0; it < 8; ++it)
        img[tid + it * 256] = img_g[tid + it * 256];
    if (tid < 128) img[2048 + tid] = img_g[2048 + tid];

    // ---- convert chunk0 while the barrier drains ---------------------------
    float xn = dot4(a0) + dot4(a1) + dot4(a2) + dot4(a3);
    long blo = pk8(a0, a1, 1.0f), bhi = pk8(a2, a3, 1.0f);
    __syncthreads();

    const long*  cb8 = (const long*)img;
    const f32x4* wn4 = img + 2048;

    // per-lane read slots (R8-proven conflict-free)
    const int key  = (lane15 >> 1) & 7;
    const int base = (lane15 >> 1) * 16 + (lane15 & 1) * 8;
    const int slo  = base + (half ^ key);          // dims [8*half, +8)
    const int shi  = slo ^ 4;                      // dims [32+8*half, +8)
    const unsigned hb   = (unsigned)(half * 4);
    const unsigned mask = 0xFFFFFE00u;

    float lossAcc = 0.f;
    float4 n0, n1, n2, n3;

    #pragma unroll
    for (int ch = 0; ch < 4; ++ch) {
        // issue next chunk's loads: VMEM busy during this chunk's score
        if (ch < 3) {
            const float* xp = xc + (ch + 1) * 1024;
            n0 = *(const float4*)xp;        n1 = *(const float4*)(xp + 4);
            n2 = *(const float4*)(xp + 32); n3 = *(const float4*)(xp + 36);
        }

        // ---- score 512 codewords; packed (score|k) min in float domain ----
        float run = __uint_as_float(0x7F7FFFFFu);
        #pragma unroll 8
        for (int t = 0; t < 32; ++t) {
            long  alo = cb8[t * 128 + slo];
            long  ahi = cb8[t * 128 + shi];
            f32x4 wnv = wn4[t * 4 + half];
            const unsigned kb = (unsigned)(t * 16) | hb;

            f32x4 acc = wnv;   // acc = 256*(1+0.5||w||^2 - x.w) = 256*score > 0
            acc = __builtin_amdgcn_mfma_f32_16x16x32_fp8_fp8(alo, blo, acc, 0, 0, 0);
            acc = __builtin_amdgcn_mfma_f32_16x16x32_fp8_fp8(ahi, bhi, acc, 0, 0, 0);
            float p0 = __uint_as_float((__float_as_uint(acc[0]) & mask) | kb);
            float p1 = __uint_as_float((__float_as_uint(acc[1]) & mask) | (kb | 1u));
            float p2 = __uint_as_float((__float_as_uint(acc[2]) & mask) | (kb | 2u));
            float p3 = __uint_as_float((__float_as_uint(acc[3]) & mask) | (kb | 3u));
            run = fminf(fminf(fminf(p0, p1), p2), fminf(run, p3));
        }

        // ---- reduce across 4 halves (same lane15 = same x-row) -------------
        run = fminf(run, __shfl_xor(run, 16));
        run = fminf(run, __shfl_xor(run, 32));
        float xs = xn;
        xs += __shfl_xor(xs, 16); xs += __shfl_xor(xs, 32);

        const unsigned f0 = __float_as_uint(run);
        // packed score = 256*(1+0.5||q||^2-x.q); ||x-q||^2 = xs + pf/128 - 2
        // 4 dup lanes x 0.25 -> wave sum = sum_rows ||x-q||^2 (proven)
        float pf = __uint_as_float(f0 & mask);
        lossAcc += 0.25f * (xs + pf * (1.0f / 128.0f) - 2.0f);
        const int bk0 = (int)(f0 & 511u);

        // ---- gather + store this chunk (drains under next chunk's score) ---
        float* outw = out + (size_t)(wrow + ch * 16) * DIM;
        #pragma unroll
        for (int j = 0; j < 4; ++j) {
            const int srcl = (j * 4 + half) & 15;
            int bk = __shfl(bk0, srcl);
            f32x4 qv = *(const f32x4*)(cb + (size_t)bk * DIM + lane15 * 4);
            *(f32x4*)(outw + j * 256 + lane * 4) = qv;
        }

        // ---- convert prefetched chunk (loads complete by now) --------------
        if (ch < 3) {
            xn  = dot4(n0) + dot4(n1) + dot4(n2) + dot4(n3);
            blo = pk8(n0, n1, 1.0f);
            bhi = pk8(n2, n3, 1.0f);
        }
    }

    // ---- loss partial ------------------------------------------------------
    #pragma unroll
    for (int off = 1; off < 64; off <<= 1) lossAcc += __shfl_xor(lossAcc, off);
    if (lane == 0) red_sh[wave] = lossAcc;
    __syncthreads();
    if (tid == 0) {
        float s = red_sh[0] + red_sh[1] + red_sh[2] + red_sh[3];
        partials[blockIdx.x] = s;
    }
}

// ---- kernel 2: final loss reduction (1024 partials) ------------------------
__global__ void vq_finalize(const float* __restrict__ partials,
                            float* __restrict__ out_loss) {
    __shared__ float sh[256];
    int t = threadIdx.x;
    sh[t] = partials[t] + partials[t + 256] + partials[t + 512] + partials[t + 768];
    __syncthreads();
    #pragma unroll
    for (int s = 128; s > 0; s >>= 1) {
        if (t < s) sh[t] += sh[t + s];
        __syncthreads();
    }
    // partials = sum_rows ||x-q||^2 ; vq_loss = 1.25 * sum / (N*D)
    if (t == 0) out_loss[0] = sh[0] * (1.25f / (float)(N_ROWS * DIM));
}

extern "C" void kernel_launch(void* const* d_in, const int* in_sizes, int n_in,
                              void* d_out, int out_size, void* d_ws, size_t ws_size,
                              hipStream_t stream) {
    const float* x  = (const float*)d_in[0];
    const float* cb = (const float*)d_in[1];
    float* out      = (float*)d_out;
    long*  ws_cb8   = (long*)d_ws;                          // 4096 longs (32 KiB)
    float* ws_wn    = (float*)((char*)d_ws + 32768);        // 512 floats (2 KiB)
    float* partials = (float*)((char*)d_ws + 36864);        // 1024 floats

    hipLaunchKernelGGL(vq_prep, dim3(8), dim3(512), 0, stream, cb, ws_cb8, ws_wn);
    hipLaunchKernelGGL(vq_main, dim3(MBLOCKS), dim3(MTHREADS), 0, stream,
                       x, cb, (const f32x4*)d_ws, out, partials);
    hipLaunchKernelGGL(vq_finalize, dim3(1), dim3(256), 0, stream,
                       partials, out + (size_t)N_ROWS * DIM);
}

// Round 11
// 40.005 us; speedup vs baseline: 1.2037x; 1.0080x over previous
//
#include <hip/hip_runtime.h>

#define N_ROWS 262144
#define DIM    64
#define KCB    512

#define MBLOCKS  512
#define MTHREADS 512         // 8 waves; each wave 64 rows = 4 chunks x 16

typedef float f32x4 __attribute__((ext_vector_type(4)));

__device__ inline float dot4(float4 a) {
    return a.x * a.x + a.y * a.y + a.z * a.z + a.w * a.w;
}

// pack 8 f32 (scaled) into 8 fp8-e4m3 bytes via HW cvt_pk
__device__ inline long pk8(float4 f0, float4 f1, float s) {
    int lo = 0, hi = 0;
    lo = __builtin_amdgcn_cvt_pk_fp8_f32(f0.x * s, f0.y * s, lo, false);
    lo = __builtin_amdgcn_cvt_pk_fp8_f32(f0.z * s, f0.w * s, lo, true);
    hi = __builtin_amdgcn_cvt_pk_fp8_f32(f1.x * s, f1.y * s, hi, false);
    hi = __builtin_amdgcn_cvt_pk_fp8_f32(f1.z * s, f1.w * s, hi, true);
    return (long)(((unsigned long)(unsigned)hi << 32) | (unsigned)lo);
}

// ---- kernel 0: one-time codebook pre-pack into the exact LDS image ---------
// image: longs[0..4096) = fp8(-256*w) in interleaved+swizzled slots (32 KiB),
//        floats[8192..8704) = wn[k] = 256*(1+0.5||w||^2) (2 KiB)
__global__ void vq_prep(const float* __restrict__ cb, long* __restrict__ cb8,
                        float* __restrict__ wn) {
    const int fg  = blockIdx.x * 512 + threadIdx.x;   // 0..4095
    const int row = fg >> 3, g = fg & 7;
    const float* src = cb + row * DIM + g * 8;
    float4 f0 = *(const float4*)src;
    float4 f1 = *(const float4*)(src + 4);
    float sq = dot4(f0) + dot4(f1);
    sq += __shfl_xor(sq, 1);
    sq += __shfl_xor(sq, 2);
    sq += __shfl_xor(sq, 4);
    const int slot = ((row >> 1) << 4) + ((row & 1) << 3)
                   + (g ^ ((row >> 1) & 7));
    cb8[slot] = pk8(f0, f1, -256.0f);
    if (g == 0) wn[row] = 256.0f + 128.0f * sq;
}

// ---- kernel 1: fused, 4-chunk pipelined: load(i+1) | score(i) | store(i) ---
__global__ __launch_bounds__(MTHREADS, 2) void vq_main(
    const float* __restrict__ x, const float* __restrict__ cb,
    const f32x4* __restrict__ img_g, float* __restrict__ out,
    float* __restrict__ partials)
{
    __shared__ f32x4 img[2176];            // 34 KiB: cb8[2048] + wn[128]
    __shared__ float red_sh[8];

    const int tid    = threadIdx.x;
    const int lane   = tid & 63;
    const int wave   = tid >> 6;           // 0..7
    const int lane15 = lane & 15;
    const int half   = lane >> 4;          // 0..3

    const int wrow = blockIdx.x * 512 + wave * 64;
    const float* xc = x + (size_t)(wrow + lane15) * DIM + half * 8;

    // ---- issue chunk0 x loads (in flight during staging) -------------------
    float4 a0 = *(const float4*)xc,        a1 = *(const float4*)(xc + 4);
    float4 a2 = *(const float4*)(xc + 32), a3 = *(const float4*)(xc + 36);

    // ---- stage pre-packed image: pure linear 34 KiB copy, zero convert -----
    #pragma unroll
    for (int it = 0; it < 4; ++it)
        img[tid + it * 512] = img_g[tid + it * 512];
    if (tid < 128) img[2048 + tid] = img_g[2048 + tid];

    // ---- convert chunk0 while the barrier drains ---------------------------
    float xn = dot4(a0) + dot4(a1) + dot4(a2) + dot4(a3);
    long blo = pk8(a0, a1, 1.0f), bhi = pk8(a2, a3, 1.0f);
    __syncthreads();

    const long*  cb8 = (const long*)img;
    const f32x4* wn4 = img + 2048;

    // per-lane read slots (R8-proven conflict-free)
    const int key  = (lane15 >> 1) & 7;
    const int base = (lane15 >> 1) * 16 + (lane15 & 1) * 8;
    const int slo  = base + (half ^ key);          // dims [8*half, +8)
    const int shi  = slo ^ 4;                      // dims [32+8*half, +8)
    const unsigned hb   = (unsigned)(half * 4);
    const unsigned mask = 0xFFFFFE00u;

    float lossAcc = 0.f;
    float4 n0, n1, n2, n3;

    #pragma unroll
    for (int ch = 0; ch < 4; ++ch) {
        // issue next chunk's loads: VMEM busy during this chunk's score
        if (ch < 3) {
            const float* xp = xc + (ch + 1) * 1024;
            n0 = *(const float4*)xp;        n1 = *(const float4*)(xp + 4);
            n2 = *(const float4*)(xp + 32); n3 = *(const float4*)(xp + 36);
        }

        // ---- score 512 codewords; packed (score|k) min in float domain ----
        float run = __uint_as_float(0x7F7FFFFFu);
        #pragma unroll 8
        for (int t = 0; t < 32; ++t) {
            long  alo = cb8[t * 128 + slo];
            long  ahi = cb8[t * 128 + shi];
            f32x4 wnv = wn4[t * 4 + half];
            const unsigned kb = (unsigned)(t * 16) | hb;

            f32x4 acc = wnv;   // acc = 256*(1+0.5||w||^2 - x.w) = 256*score > 0
            acc = __builtin_amdgcn_mfma_f32_16x16x32_fp8_fp8(alo, blo, acc, 0, 0, 0);
            acc = __builtin_amdgcn_mfma_f32_16x16x32_fp8_fp8(ahi, bhi, acc, 0, 0, 0);
            float p0 = __uint_as_float((__float_as_uint(acc[0]) & mask) | kb);
            float p1 = __uint_as_float((__float_as_uint(acc[1]) & mask) | (kb | 1u));
            float p2 = __uint_as_float((__float_as_uint(acc[2]) & mask) | (kb | 2u));
            float p3 = __uint_as_float((__float_as_uint(acc[3]) & mask) | (kb | 3u));
            run = fminf(fminf(fminf(p0, p1), p2), fminf(run, p3));
        }

        // ---- reduce across 4 halves (same lane15 = same x-row) -------------
        run = fminf(run, __shfl_xor(run, 16));
        run = fminf(run, __shfl_xor(run, 32));
        float xs = xn;
        xs += __shfl_xor(xs, 16); xs += __shfl_xor(xs, 32);

        const unsigned f0 = __float_as_uint(run);
        // packed score = 256*(1+0.5||q||^2-x.q); ||x-q||^2 = xs + pf/128 - 2
        // 4 dup lanes x 0.25 -> wave sum = sum_rows ||x-q||^2 (proven)
        float pf = __uint_as_float(f0 & mask);
        lossAcc += 0.25f * (xs + pf * (1.0f / 128.0f) - 2.0f);
        const int bk0 = (int)(f0 & 511u);

        // ---- gather + store this chunk (drains under next chunk's score) ---
        float* outw = out + (size_t)(wrow + ch * 16) * DIM;
        #pragma unroll
        for (int j = 0; j < 4; ++j) {
            const int srcl = (j * 4 + half) & 15;
            int bk = __shfl(bk0, srcl);
            f32x4 qv = *(const f32x4*)(cb + (size_t)bk * DIM + lane15 * 4);
            *(f32x4*)(outw + j * 256 + lane * 4) = qv;
        }

        // ---- convert prefetched chunk (loads complete by now) --------------
        if (ch < 3) {
            xn  = dot4(n0) + dot4(n1) + dot4(n2) + dot4(n3);
            blo = pk8(n0, n1, 1.0f);
            bhi = pk8(n2, n3, 1.0f);
        }
    }

    // ---- loss partial ------------------------------------------------------
    #pragma unroll
    for (int off = 1; off < 64; off <<= 1) lossAcc += __shfl_xor(lossAcc, off);
    if (lane == 0) red_sh[wave] = lossAcc;
    __syncthreads();
    if (tid == 0) {
        float s = 0.f;
        #pragma unroll
        for (int w = 0; w < 8; ++w) s += red_sh[w];
        partials[blockIdx.x] = s;
    }
}

// ---- kernel 2: final loss reduction (512 partials) -------------------------
__global__ void vq_finalize(const float* __restrict__ partials,
                            float* __restrict__ out_loss) {
    __shared__ float sh[256];
    int t = threadIdx.x;
    sh[t] = partials[t] + partials[t + 256];
    __syncthreads();
    #pragma unroll
    for (int s = 128; s > 0; s >>= 1) {
        if (t < s) sh[t] += sh[t + s];
        __syncthreads();
    }
    // partials = sum_rows ||x-q||^2 ; vq_loss = 1.25 * sum / (N*D)
    if (t == 0) out_loss[0] = sh[0] * (1.25f / (float)(N_ROWS * DIM));
}

extern "C" void kernel_launch(void* const* d_in, const int* in_sizes, int n_in,
                              void* d_out, int out_size, void* d_ws, size_t ws_size,
                              hipStream_t stream) {
    const float* x  = (const float*)d_in[0];
    const float* cb = (const float*)d_in[1];
    float* out      = (float*)d_out;
    long*  ws_cb8   = (long*)d_ws;                          // 4096 longs (32 KiB)
    float* ws_wn    = (float*)((char*)d_ws + 32768);        // 512 floats (2 KiB)
    float* partials = (float*)((char*)d_ws + 36864);        // 512 floats

    hipLaunchKernelGGL(vq_prep, dim3(8), dim3(512), 0, stream, cb, ws_cb8, ws_wn);
    hipLaunchKernelGGL(vq_main, dim3(MBLOCKS), dim3(MTHREADS), 0, stream,
                       x, cb, (const f32x4*)d_ws, out, partials);
    hipLaunchKernelGGL(vq_finalize, dim3(1), dim3(256), 0, stream,
                       partials, out + (size_t)N_ROWS * DIM);
}

// Round 12
// 39.266 us; speedup vs baseline: 1.2264x; 1.0188x over previous
//
#include <hip/hip_runtime.h>

#define N_ROWS 262144
#define DIM    64
#define KCB    512

#define MBLOCKS  512
#define MTHREADS 512         // 8 waves; each wave 64 rows = 4 chunks x 16

typedef float f32x4 __attribute__((ext_vector_type(4)));

__device__ inline float dot4(float4 a) {
    return a.x * a.x + a.y * a.y + a.z * a.z + a.w * a.w;
}

// pack 8 f32 (scaled) into 8 fp8-e4m3 bytes via HW cvt_pk
__device__ inline long pk8(float4 f0, float4 f1, float s) {
    int lo = 0, hi = 0;
    lo = __builtin_amdgcn_cvt_pk_fp8_f32(f0.x * s, f0.y * s, lo, false);
    lo = __builtin_amdgcn_cvt_pk_fp8_f32(f0.z * s, f0.w * s, lo, true);
    hi = __builtin_amdgcn_cvt_pk_fp8_f32(f1.x * s, f1.y * s, hi, false);
    hi = __builtin_amdgcn_cvt_pk_fp8_f32(f1.z * s, f1.w * s, hi, true);
    return (long)(((unsigned long)(unsigned)hi << 32) | (unsigned)lo);
}

// pack candidates (score|k) and fold into running min (float-domain monotone)
__device__ inline float packmin(f32x4 acc, unsigned kb, float run) {
    const unsigned mask = 0xFFFFFE00u;
    float p0 = __uint_as_float((__float_as_uint(acc[0]) & mask) | kb);
    float p1 = __uint_as_float((__float_as_uint(acc[1]) & mask) | (kb | 1u));
    float p2 = __uint_as_float((__float_as_uint(acc[2]) & mask) | (kb | 2u));
    float p3 = __uint_as_float((__float_as_uint(acc[3]) & mask) | (kb | 3u));
    return fminf(fminf(fminf(p0, p1), p2), fminf(run, p3));
}

// ---- kernel 0: one-time codebook pre-pack into the exact LDS image ---------
__global__ void vq_prep(const float* __restrict__ cb, long* __restrict__ cb8,
                        float* __restrict__ wn) {
    const int fg  = blockIdx.x * 512 + threadIdx.x;   // 0..4095
    const int row = fg >> 3, g = fg & 7;
    const float* src = cb + row * DIM + g * 8;
    float4 f0 = *(const float4*)src;
    float4 f1 = *(const float4*)(src + 4);
    float sq = dot4(f0) + dot4(f1);
    sq += __shfl_xor(sq, 1);
    sq += __shfl_xor(sq, 2);
    sq += __shfl_xor(sq, 4);
    const int slot = ((row >> 1) << 4) + ((row & 1) << 3)
                   + (g ^ ((row >> 1) & 7));
    cb8[slot] = pk8(f0, f1, -256.0f);
    if (g == 0) wn[row] = 256.0f + 128.0f * sq;
}

// ---- kernel 1: single score loop, 4 chunks share every LDS read ------------
__global__ __launch_bounds__(MTHREADS, 2) void vq_main(
    const float* __restrict__ x, const float* __restrict__ cb,
    const f32x4* __restrict__ img_g, float* __restrict__ out,
    float* __restrict__ partials)
{
    __shared__ f32x4 img[2176];            // 34 KiB: cb8[2048] + wn[128]
    __shared__ float red_sh[8];

    const int tid    = threadIdx.x;
    const int lane   = tid & 63;
    const int wave   = tid >> 6;           // 0..7
    const int lane15 = lane & 15;
    const int half   = lane >> 4;          // 0..3

    const int wrow = blockIdx.x * 512 + wave * 64;
    const float* xc = x + (size_t)(wrow + lane15) * DIM + half * 8;

    // ---- issue ALL x loads (16 dwordx4, in flight during staging) ----------
    float4 a[4][4];
    #pragma unroll
    for (int c = 0; c < 4; ++c) {
        const float* xp = xc + c * 1024;
        a[c][0] = *(const float4*)xp;        a[c][1] = *(const float4*)(xp + 4);
        a[c][2] = *(const float4*)(xp + 32); a[c][3] = *(const float4*)(xp + 36);
    }

    // ---- stage pre-packed image: pure linear 34 KiB copy -------------------
    #pragma unroll
    for (int it = 0; it < 4; ++it)
        img[tid + it * 512] = img_g[tid + it * 512];
    if (tid < 128) img[2048 + tid] = img_g[2048 + tid];

    // ---- convert all 4 chunks while the barrier drains ---------------------
    float xn[4];
    long  blo[4], bhi[4];
    #pragma unroll
    for (int c = 0; c < 4; ++c) {
        xn[c]  = dot4(a[c][0]) + dot4(a[c][1]) + dot4(a[c][2]) + dot4(a[c][3]);
        blo[c] = pk8(a[c][0], a[c][1], 1.0f);
        bhi[c] = pk8(a[c][2], a[c][3], 1.0f);
    }
    __syncthreads();

    const long*  cb8 = (const long*)img;
    const f32x4* wn4 = img + 2048;

    // per-lane read slots (R8-proven conflict-free)
    const int key  = (lane15 >> 1) & 7;
    const int base = (lane15 >> 1) * 16 + (lane15 & 1) * 8;
    const int slo  = base + (half ^ key);          // dims [8*half, +8)
    const int shi  = slo ^ 4;                      // dims [32+8*half, +8)
    const unsigned hb   = (unsigned)(half * 4);
    const unsigned mask = 0xFFFFFE00u;

    float run0 = __uint_as_float(0x7F7FFFFFu);
    float run1 = run0, run2 = run0, run3 = run0;

    // ---- ONE score loop: each LDS read feeds 4 chunk-MFMA chains -----------
    #pragma unroll 4
    for (int t = 0; t < 32; ++t) {
        long  alo = cb8[t * 128 + slo];
        long  ahi = cb8[t * 128 + shi];
        f32x4 wnv = wn4[t * 4 + half];
        const unsigned kb = (unsigned)(t * 16) | hb;

        f32x4 c0 = wnv;    // acc = 256*(1+0.5||w||^2 - x.w) = 256*score > 0
        c0 = __builtin_amdgcn_mfma_f32_16x16x32_fp8_fp8(alo, blo[0], c0, 0, 0, 0);
        c0 = __builtin_amdgcn_mfma_f32_16x16x32_fp8_fp8(ahi, bhi[0], c0, 0, 0, 0);
        run0 = packmin(c0, kb, run0);

        f32x4 c1 = wnv;
        c1 = __builtin_amdgcn_mfma_f32_16x16x32_fp8_fp8(alo, blo[1], c1, 0, 0, 0);
        c1 = __builtin_amdgcn_mfma_f32_16x16x32_fp8_fp8(ahi, bhi[1], c1, 0, 0, 0);
        run1 = packmin(c1, kb, run1);

        f32x4 c2 = wnv;
        c2 = __builtin_amdgcn_mfma_f32_16x16x32_fp8_fp8(alo, blo[2], c2, 0, 0, 0);
        c2 = __builtin_amdgcn_mfma_f32_16x16x32_fp8_fp8(ahi, bhi[2], c2, 0, 0, 0);
        run2 = packmin(c2, kb, run2);

        f32x4 c3 = wnv;
        c3 = __builtin_amdgcn_mfma_f32_16x16x32_fp8_fp8(alo, blo[3], c3, 0, 0, 0);
        c3 = __builtin_amdgcn_mfma_f32_16x16x32_fp8_fp8(ahi, bhi[3], c3, 0, 0, 0);
        run3 = packmin(c3, kb, run3);
    }

    // ---- per-chunk: cross-half reduce, loss, coalesced gather+store --------
    float runs[4] = {run0, run1, run2, run3};
    float lossAcc = 0.f;
    #pragma unroll
    for (int c = 0; c < 4; ++c) {
        float r = runs[c];
        r = fminf(r, __shfl_xor(r, 16));
        r = fminf(r, __shfl_xor(r, 32));
        float xs = xn[c];
        xs += __shfl_xor(xs, 16); xs += __shfl_xor(xs, 32);

        const unsigned f0 = __float_as_uint(r);
        // packed score = 256*(1+0.5||q||^2-x.q); ||x-q||^2 = xs + pf/128 - 2
        // 4 dup lanes x 0.25 -> wave sum = sum_rows ||x-q||^2 (proven)
        float pf = __uint_as_float(f0 & mask);
        lossAcc += 0.25f * (xs + pf * (1.0f / 128.0f) - 2.0f);
        const int bk0 = (int)(f0 & 511u);

        float* outw = out + (size_t)(wrow + c * 16) * DIM;
        #pragma unroll
        for (int j = 0; j < 4; ++j) {
            const int srcl = (j * 4 + half) & 15;
            int bk = __shfl(bk0, srcl);
            f32x4 qv = *(const f32x4*)(cb + (size_t)bk * DIM + lane15 * 4);
            *(f32x4*)(outw + j * 256 + lane * 4) = qv;
        }
    }

    // ---- loss partial ------------------------------------------------------
    #pragma unroll
    for (int off = 1; off < 64; off <<= 1) lossAcc += __shfl_xor(lossAcc, off);
    if (lane == 0) red_sh[wave] = lossAcc;
    __syncthreads();
    if (tid == 0) {
        float s = 0.f;
        #pragma unroll
        for (int w = 0; w < 8; ++w) s += red_sh[w];
        partials[blockIdx.x] = s;
    }
}

// ---- kernel 2: final loss reduction (512 partials) -------------------------
__global__ void vq_finalize(const float* __restrict__ partials,
                            float* __restrict__ out_loss) {
    __shared__ float sh[256];
    int t = threadIdx.x;
    sh[t] = partials[t] + partials[t + 256];
    __syncthreads();
    #pragma unroll
    for (int s = 128; s > 0; s >>= 1) {
        if (t < s) sh[t] += sh[t + s];
        __syncthreads();
    }
    // partials = sum_rows ||x-q||^2 ; vq_loss = 1.25 * sum / (N*D)
    if (t == 0) out_loss[0] = sh[0] * (1.25f / (float)(N_ROWS * DIM));
}

extern "C" void kernel_launch(void* const* d_in, const int* in_sizes, int n_in,
                              void* d_out, int out_size, void* d_ws, size_t ws_size,
                              hipStream_t stream) {
    const float* x  = (const float*)d_in[0];
    const float* cb = (const float*)d_in[1];
    float* out      = (float*)d_out;
    long*  ws_cb8   = (long*)d_ws;                          // 4096 longs (32 KiB)
    float* ws_wn    = (float*)((char*)d_ws + 32768);        // 512 floats (2 KiB)
    float* partials = (float*)((char*)d_ws + 36864);        // 512 floats

    hipLaunchKernelGGL(vq_prep, dim3(8), dim3(512), 0, stream, cb, ws_cb8, ws_wn);
    hipLaunchKernelGGL(vq_main, dim3(MBLOCKS), dim3(MTHREADS), 0, stream,
                       x, cb, (const f32x4*)d_ws, out, partials);
    hipLaunchKernelGGL(vq_finalize, dim3(1), dim3(256), 0, stream,
                       partials, out + (size_t)N_ROWS * DIM);
}